// Round 2
// baseline (708.831 us; speedup 1.0000x reference)
//
#include <hip/hip_runtime.h>

// GAE forward on MI355X.
// Pipeline: cast -> t1T=W1T@featT -> h1=relu(adj@t1+b1) [split-K] ->
//           t2T=W2T@h1T -> h=adj@t2+b2 [split-K] -> out=sigmoid(h@hT), h.
// All MFMA GEMMs use the "bt" convention: X[M,K], Y[N,K] row-major, C = X*Y^T.
// Frag layout (m89-verified): A/B lane = X[l16][k+q*8..+8] (16B load);
// C/D: col = lane&15, row = q*4 + reg.
//
// R5 (this round = R4 with compile fix):
//  - NT (non-temporal) stores for every write-once stream: sigmoid out,
//    split-K partials, fp32 h tail. NT loads for read-once partials in the
//    epilogues. NT vector ops must use clang ext_vector types (f32x4_t),
//    NOT HIP_vector_type float4 (compile error) — hence nt_load4/nt_store4.
//  - adj GEMM: 32-row tiles, grid (256,4) = 1024 blocks, launch_bounds(256,3)
//    -> 3 blocks/CU: 3 independent DMA/barrier groups per CU so one block's
//    compute covers another's vmcnt(0) drain at the __syncthreads.

typedef __bf16 bf16x8_t __attribute__((ext_vector_type(8)));
typedef __bf16 bf16x4_t __attribute__((ext_vector_type(4)));
typedef float  f32x4_t  __attribute__((ext_vector_type(4)));

#define MFMA_BF16(a, b, c) __builtin_amdgcn_mfma_f32_16x16x32_bf16((a), (b), (c), 0, 0, 0)

__device__ __forceinline__ bf16x8_t cvt8(f32x4_t u, f32x4_t v) {
    bf16x8_t o;
    o[0] = (__bf16)u[0]; o[1] = (__bf16)u[1]; o[2] = (__bf16)u[2]; o[3] = (__bf16)u[3];
    o[4] = (__bf16)v[0]; o[5] = (__bf16)v[1]; o[6] = (__bf16)v[2]; o[7] = (__bf16)v[3];
    return o;
}

__device__ __forceinline__ f32x4_t nt_load4(const float* p) {
    return __builtin_nontemporal_load((const f32x4_t*)p);
}
__device__ __forceinline__ void nt_store4(f32x4_t v, float* p) {
    __builtin_nontemporal_store(v, (f32x4_t*)p);
}

// width-16 global->LDS DMA; AUX=2 sets the non-temporal cache policy
template<int AUX>
__device__ __forceinline__ void gload_lds16(const float* g, float* l) {
    __builtin_amdgcn_global_load_lds(
        (const __attribute__((address_space(1))) unsigned int*)g,
        (__attribute__((address_space(3))) unsigned int*)l, 16, 0, AUX);
}

// ---- cast feature -> bf16 (8 elems/thread), W1 -> W1T bf16, W2 -> W2T bf16 ----
__global__ __launch_bounds__(256) void cast_all(
    const float* __restrict__ feat, const float* __restrict__ W1,
    const float* __restrict__ W2, __bf16* __restrict__ fb,
    __bf16* __restrict__ w1t, __bf16* __restrict__ w2t)
{
    const int j = blockIdx.x * 256 + threadIdx.x;
    if (j < 524288) {                     // feature: 8192*512 / 8
        const float* p = feat + (size_t)j * 8;
        f32x4_t u = nt_load4(p);
        f32x4_t v = nt_load4(p + 4);
        *(bf16x8_t*)(fb + (size_t)j * 8) = cvt8(u, v);
    } else if (j < 524288 + 131072) {     // W1 [512][256] -> W1T [256][512]
        int t = j - 524288;
        int k = t >> 8, n = t & 255;
        w1t[n * 512 + k] = (__bf16)W1[t];
    } else if (j < 524288 + 131072 + 32768) { // W2 [256][128] -> W2T [128][256]
        int t = j - 655360;
        int k = t >> 7, n = t & 127;
        w2t[n * 256 + k] = (__bf16)W2[t];
    }
}

// ---- small bf16 GEMM, C (bf16) = X * Y^T ----
template<int MT, int WC>
__global__ __launch_bounds__(256, 2) void gemm_bt_cbf16(
    const __bf16* __restrict__ X, const __bf16* __restrict__ Yb,
    __bf16* __restrict__ C, int K, int N)
{
    constexpr int WR = 4 / WC;
    constexpr int BM = WR * MT * 16;
    constexpr int BN = WC * 64;
    const int mblk = blockIdx.x, nblk = blockIdx.y;
    const int w = threadIdx.x >> 6, lane = threadIdx.x & 63;
    const int wr = w / WC, wc = w % WC;
    const int q = lane >> 4, l16 = lane & 15;
    const int mbase = mblk * BM + wr * (MT * 16);
    const int nbase = nblk * BN + wc * 64;

    f32x4_t acc[MT][4];
    const f32x4_t z = {0.f, 0.f, 0.f, 0.f};
#pragma unroll
    for (int i = 0; i < MT; i++)
#pragma unroll
        for (int jj = 0; jj < 4; jj++) acc[i][jj] = z;

    const __bf16* Xr[MT];
    const __bf16* Yr[4];
#pragma unroll
    for (int i = 0; i < MT; i++) Xr[i] = X + (size_t)(mbase + i * 16 + l16) * K + q * 8;
#pragma unroll
    for (int jj = 0; jj < 4; jj++) Yr[jj] = Yb + (size_t)(nbase + jj * 16 + l16) * K + q * 8;

    for (int k = 0; k < K; k += 32) {
        bf16x8_t a[MT], b[4];
#pragma unroll
        for (int i = 0; i < MT; i++) a[i] = *(const bf16x8_t*)(Xr[i] + k);
#pragma unroll
        for (int jj = 0; jj < 4; jj++) b[jj] = *(const bf16x8_t*)(Yr[jj] + k);
#pragma unroll
        for (int i = 0; i < MT; i++)
#pragma unroll
            for (int jj = 0; jj < 4; jj++) acc[i][jj] = MFMA_BF16(a[i], b[jj], acc[i][jj]);
    }

#pragma unroll
    for (int i = 0; i < MT; i++)
#pragma unroll
        for (int jj = 0; jj < 4; jj++) {
            const int row0 = mbase + i * 16 + q * 4;
            const int col = nbase + jj * 16 + l16;
#pragma unroll
            for (int r = 0; r < 4; r++)
                C[(size_t)(row0 + r) * N + col] = (__bf16)acc[i][jj][r];
        }
}

// ---- adj GEMM: fp32 A staged via NT global_load_lds into double-buffered LDS
// (32x64 tile, 8 KB x2), source-column XOR swizzle @16B. Wave-grid 1x4: each
// wave computes all 32 rows x NN/4 cols. B (Y) loaded per-wave from global,
// L2-resident since adj is NT and partials are NT-stored. 3 blocks/CU. ----
template<int NN>
__global__ __launch_bounds__(256, 3) void gemm_adj_lds(
    const float* __restrict__ A, const __bf16* __restrict__ Y,
    float* __restrict__ P, int kchunk)
{
    constexpr int NT = NN / 64;          // n-tiles per wave (1x4 wave grid)
    __shared__ float As[2][2048];        // 2 x 32 rows x 64 cols fp32 = 16 KB

    const int mblk = blockIdx.x;         // 256 blocks of 32 rows
    const int ks = blockIdx.y;
    const int w = threadIdx.x >> 6, lane = threadIdx.x & 63;
    const int q = lane >> 4, l16 = lane & 15;
    const int kbase = ks * kchunk;
    const int ntiles = kchunk >> 6;

    // staging: wave-instr (w, j) covers tile rows j*16+w*4 .. +4.
    // LDS dst = uniform base + lane*16 (DMA constraint); global source column
    // XOR-swizzled: granule g at row r holds A[.., kk + ((g ^ (r&15))*4)].
    const int lrow = lane >> 4;
    const int lg = lane & 15;
    const float* gsrc[2];
    int loff[2];
#pragma unroll
    for (int j = 0; j < 2; j++) {
        const int row = j * 16 + w * 4 + lrow;
        const int colswz = ((lg ^ (row & 15)) << 2);
        gsrc[j] = A + (size_t)(mblk * 32 + row) * 8192 + kbase + colswz;
        loff[j] = row * 64 + (lg << 2);
    }

    const __bf16* Yr[NT];
#pragma unroll
    for (int jj = 0; jj < NT; jj++)
        Yr[jj] = Y + (size_t)(w * (NN / 4) + jj * 16 + l16) * 8192 + q * 8;

    f32x4_t acc[2][NT];
    const f32x4_t z = {0.f, 0.f, 0.f, 0.f};
#pragma unroll
    for (int i = 0; i < 2; i++)
#pragma unroll
        for (int jj = 0; jj < NT; jj++) acc[i][jj] = z;

    // preload tile 0 (NT cpol: don't pollute L2 with streaming adj)
#pragma unroll
    for (int j = 0; j < 2; j++) gload_lds16<2>(gsrc[j], &As[0][0] + loff[j]);

    int buf = 0;
    for (int kt = 0; kt < ntiles; kt++) {
        const int kk = kbase + (kt << 6);

        // B fragments for this K-tile, issued BEFORE the barrier: they are
        // L2-hits and complete during the barrier's DMA drain.
        bf16x8_t breg[2][NT];
#pragma unroll
        for (int s = 0; s < 2; s++)
#pragma unroll
            for (int jj = 0; jj < NT; jj++)
                breg[s][jj] = *(const bf16x8_t*)(Yr[jj] + kk + s * 32);

        __syncthreads();   // tile kt DMA complete; prev compute done

        if (kt + 1 < ntiles) {
            const int koff = (kt + 1) << 6;
#pragma unroll
            for (int j = 0; j < 2; j++)
                gload_lds16<2>(gsrc[j] + koff, &As[buf ^ 1][0] + loff[j]);
        }

        const float* __restrict__ L = &As[buf][0];
#pragma unroll
        for (int s = 0; s < 2; s++) {
            bf16x8_t a[2];
#pragma unroll
            for (int i = 0; i < 2; i++) {
                const int r = i * 16 + l16;              // tile-local row
                const int g0 = ((s * 8 + q * 2) ^ l16) << 2;
                const int g1 = ((s * 8 + q * 2 + 1) ^ l16) << 2;
                f32x4_t u = *(const f32x4_t*)(L + r * 64 + g0);
                f32x4_t v = *(const f32x4_t*)(L + r * 64 + g1);
                a[i] = cvt8(u, v);
            }
#pragma unroll
            for (int i = 0; i < 2; i++)
#pragma unroll
                for (int jj = 0; jj < NT; jj++)
                    acc[i][jj] = MFMA_BF16(a[i], breg[s][jj], acc[i][jj]);
        }
        buf ^= 1;
    }

    // NT partial stores: write-once stream, don't evict the B panel from L2
#pragma unroll
    for (int i = 0; i < 2; i++)
#pragma unroll
        for (int jj = 0; jj < NT; jj++) {
            const int row0 = mblk * 32 + i * 16 + q * 4;
            const int col = w * (NN / 4) + jj * 16 + l16;
            float* pp = P + ((size_t)ks * 8192 + row0) * NN + col;
#pragma unroll
            for (int r = 0; r < 4; r++)
                __builtin_nontemporal_store(acc[i][jj][r], pp + (size_t)r * NN);
        }
}

// ---- epilogue 1: h1 = relu(sum_ks partial + b1) -> bf16 [8192][256] ----
__global__ __launch_bounds__(256) void epi_relu_bias(
    const float* __restrict__ P, const float* __restrict__ bias,
    __bf16* __restrict__ H)
{
    const size_t SL = (size_t)8192 * 256;
    const size_t idx = ((size_t)blockIdx.x * 256 + threadIdx.x) * 4;
    f32x4_t s0 = nt_load4(P + idx);
    f32x4_t s1 = nt_load4(P + SL + idx);
    f32x4_t s2 = nt_load4(P + 2 * SL + idx);
    f32x4_t s3 = nt_load4(P + 3 * SL + idx);
    const int col = (int)(idx & 255);
    f32x4_t bb = *(const f32x4_t*)(bias + col);
    bf16x4_t o;
#pragma unroll
    for (int e = 0; e < 4; e++)
        o[e] = (__bf16)fmaxf(s0[e] + s1[e] + s2[e] + s3[e] + bb[e], 0.f);
    *(bf16x4_t*)(H + idx) = o;   // cacheable: re-read by t2T GEMM
}

// ---- epilogue 2: h = sum_ks partial + b2 -> fp32 d_out tail AND bf16 copy ----
__global__ __launch_bounds__(256) void epi_bias_out(
    const float* __restrict__ P, const float* __restrict__ bias,
    float* __restrict__ Hout, __bf16* __restrict__ Hbf)
{
    const size_t SL = (size_t)8192 * 128;
    const size_t idx = ((size_t)blockIdx.x * 256 + threadIdx.x) * 4;
    f32x4_t s0 = nt_load4(P + idx);
    f32x4_t s1 = nt_load4(P + SL + idx);
    f32x4_t s2 = nt_load4(P + 2 * SL + idx);
    f32x4_t s3 = nt_load4(P + 3 * SL + idx);
    const int col = (int)(idx & 127);
    f32x4_t bb = *(const f32x4_t*)(bias + col);
    f32x4_t o;
#pragma unroll
    for (int e = 0; e < 4; e++)
        o[e] = s0[e] + s1[e] + s2[e] + s3[e] + bb[e];
    nt_store4(o, Hout + idx);   // write-once tail of d_out
    bf16x4_t ob;
#pragma unroll
    for (int e = 0; e < 4; e++) ob[e] = (__bf16)o[e];
    *(bf16x4_t*)(Hbf + idx) = ob;   // cacheable: re-read 128x by gemm_sig
}

// ---- decoder: out[r][s] = sigmoid(h[r,:].h[s,:]), K=128 unrolled ----
__global__ __launch_bounds__(256, 2) void gemm_sig(
    const __bf16* __restrict__ H, float* __restrict__ out)
{
    const int mblk = blockIdx.x, nblk = blockIdx.y;
    const int w = threadIdx.x >> 6, lane = threadIdx.x & 63;
    const int wr = w >> 1, wc = w & 1;
    const int q = lane >> 4, l16 = lane & 15;
    const int mbase = mblk * 128 + wr * 64;
    const int nbase = nblk * 128 + wc * 64;

    f32x4_t acc[4][4];
    const f32x4_t z = {0.f, 0.f, 0.f, 0.f};
#pragma unroll
    for (int i = 0; i < 4; i++)
#pragma unroll
        for (int jj = 0; jj < 4; jj++) acc[i][jj] = z;

#pragma unroll
    for (int k = 0; k < 128; k += 32) {
        bf16x8_t a[4], b[4];
#pragma unroll
        for (int i = 0; i < 4; i++)
            a[i] = *(const bf16x8_t*)(H + (size_t)(mbase + i * 16 + l16) * 128 + k + q * 8);
#pragma unroll
        for (int jj = 0; jj < 4; jj++)
            b[jj] = *(const bf16x8_t*)(H + (size_t)(nbase + jj * 16 + l16) * 128 + k + q * 8);
#pragma unroll
        for (int i = 0; i < 4; i++)
#pragma unroll
            for (int jj = 0; jj < 4; jj++) acc[i][jj] = MFMA_BF16(a[i], b[jj], acc[i][jj]);
    }

    // NT stores: out is a 268 MB write-once stream; keeping it out of L2
    // preserves the 2 MB H panel across the 128x re-reads.
#pragma unroll
    for (int i = 0; i < 4; i++)
#pragma unroll
        for (int jj = 0; jj < 4; jj++) {
            const int row0 = mbase + i * 16 + q * 4;
            const int col = nbase + jj * 16 + l16;
#pragma unroll
            for (int r = 0; r < 4; r++) {
                float x = acc[i][jj][r];
                float s = 1.0f / (1.0f + __expf(-x));
                __builtin_nontemporal_store(s, out + (size_t)(row0 + r) * 8192 + col);
            }
        }
}

extern "C" void kernel_launch(void* const* d_in, const int* in_sizes, int n_in,
                              void* d_out, int out_size, void* d_ws, size_t ws_size,
                              hipStream_t stream)
{
    const float* adj  = (const float*)d_in[0];
    const float* feat = (const float*)d_in[1];
    const float* W1   = (const float*)d_in[2];
    const float* b1   = (const float*)d_in[3];
    const float* W2   = (const float*)d_in[4];
    const float* b2   = (const float*)d_in[5];
    float* out = (float*)d_out;

    // workspace layout (~52.3 MB total)
    char* p = (char*)d_ws;
    __bf16* featbf = (__bf16*)p; p += (size_t)8192 * 512 * 2;  // 8 MB
    __bf16* W1T    = (__bf16*)p; p += (size_t)256 * 512 * 2;   // 256 KB
    __bf16* W2T    = (__bf16*)p; p += (size_t)128 * 256 * 2;   // 64 KB
    __bf16* t1T    = (__bf16*)p; p += (size_t)256 * 8192 * 2;  // 4 MB
    __bf16* h1     = (__bf16*)p; p += (size_t)8192 * 256 * 2;  // 4 MB
    __bf16* t2T    = (__bf16*)p; p += (size_t)128 * 8192 * 2;  // 2 MB
    __bf16* hbf    = (__bf16*)p; p += (size_t)8192 * 128 * 2;  // 2 MB
    float* part    = (float*)p;                                 // 32 MB (reused 16 MB)

    // 1. casts
    cast_all<<<2688, 256, 0, stream>>>(feat, W1, W2, featbf, W1T, W2T);
    // 2. t1T[256][8192] = W1T * feat^T
    gemm_bt_cbf16<2, 2><<<dim3(4, 64), 256, 0, stream>>>(W1T, featbf, t1T, 512, 8192);
    // 3. partials of adj @ t1  (split-K=4, LDS-staged, NT adj, 3 blocks/CU)
    gemm_adj_lds<256><<<dim3(256, 4), 256, 0, stream>>>(adj, t1T, part, 2048);
    // 4. h1 = relu(sum + b1) -> bf16
    epi_relu_bias<<<2048, 256, 0, stream>>>(part, b1, h1);
    // 5. t2T[128][8192] = W2T * h1^T
    gemm_bt_cbf16<2, 2><<<dim3(2, 64), 256, 0, stream>>>(W2T, h1, t2T, 256, 8192);
    // 6. partials of adj @ t2  (split-K=4, LDS-staged, NT adj, 3 blocks/CU)
    gemm_adj_lds<128><<<dim3(256, 4), 256, 0, stream>>>(adj, t2T, part, 2048);
    // 7. h = sum + b2 -> fp32 out tail + bf16 copy
    epi_bias_out<<<1024, 256, 0, stream>>>(part, b2, out + (size_t)8192 * 8192, hbf);
    // 8. out = sigmoid(h @ h^T)
    gemm_sig<<<dim3(64, 64), 256, 0, stream>>>(hbf, out);
}

// Round 3
// 636.697 us; speedup vs baseline: 1.1133x; 1.1133x over previous
//
#include <hip/hip_runtime.h>

// GAE forward on MI355X.
// Pipeline: cast -> t1T=W1T@featT -> h1=relu(adj@t1+b1) [split-K] ->
//           t2T=W2T@h1T -> h=adj@t2+b2 [split-K] -> out=sigmoid(h@hT), h.
// All MFMA GEMMs use the "bt" convention: X[M,K], Y[N,K] row-major, C = X*Y^T.
// Frag layout (m89-verified): A/B lane = X[l16][k+q*8..+8] (16B load);
// C/D: col = lane&15, row = q*4 + reg.
//
// R6: revert adj GEMM to the proven R3 shape (64-row tiles, MT=4, grid
// (128,4), 2 blocks/CU) — the R5 32-row re-tile doubled B-panel L2 traffic
// (512MB -> 1GB ~ 24 TB/s) and barrier-drain count, costing +80us. Keep ONLY
// the NT cache-policy changes from R5 (isolated this round):
//  - NT stores on sigmoid out (268 MB write-once; protects the 2 MB H panel
//    that gemm_sig re-reads 64x from L2),
//  - NT stores on split-K partials + NT loads in the epilogues (48 MB
//    write-once/read-once; protects the t1T/t2T B panels),
//  - NT loads on the feat cast.

typedef __bf16 bf16x8_t __attribute__((ext_vector_type(8)));
typedef __bf16 bf16x4_t __attribute__((ext_vector_type(4)));
typedef float  f32x4_t  __attribute__((ext_vector_type(4)));

#define MFMA_BF16(a, b, c) __builtin_amdgcn_mfma_f32_16x16x32_bf16((a), (b), (c), 0, 0, 0)

__device__ __forceinline__ bf16x8_t cvt8(f32x4_t u, f32x4_t v) {
    bf16x8_t o;
    o[0] = (__bf16)u[0]; o[1] = (__bf16)u[1]; o[2] = (__bf16)u[2]; o[3] = (__bf16)u[3];
    o[4] = (__bf16)v[0]; o[5] = (__bf16)v[1]; o[6] = (__bf16)v[2]; o[7] = (__bf16)v[3];
    return o;
}

__device__ __forceinline__ f32x4_t nt_load4(const float* p) {
    return __builtin_nontemporal_load((const f32x4_t*)p);
}
__device__ __forceinline__ void nt_store4(f32x4_t v, float* p) {
    __builtin_nontemporal_store(v, (f32x4_t*)p);
}

// width-16 global->LDS DMA; AUX=2 sets the non-temporal cache policy
template<int AUX>
__device__ __forceinline__ void gload_lds16(const float* g, float* l) {
    __builtin_amdgcn_global_load_lds(
        (const __attribute__((address_space(1))) unsigned int*)g,
        (__attribute__((address_space(3))) unsigned int*)l, 16, 0, AUX);
}

// ---- cast feature -> bf16 (8 elems/thread), W1 -> W1T bf16, W2 -> W2T bf16 ----
__global__ __launch_bounds__(256) void cast_all(
    const float* __restrict__ feat, const float* __restrict__ W1,
    const float* __restrict__ W2, __bf16* __restrict__ fb,
    __bf16* __restrict__ w1t, __bf16* __restrict__ w2t)
{
    const int j = blockIdx.x * 256 + threadIdx.x;
    if (j < 524288) {                     // feature: 8192*512 / 8
        const float* p = feat + (size_t)j * 8;
        f32x4_t u = nt_load4(p);
        f32x4_t v = nt_load4(p + 4);
        *(bf16x8_t*)(fb + (size_t)j * 8) = cvt8(u, v);
    } else if (j < 524288 + 131072) {     // W1 [512][256] -> W1T [256][512]
        int t = j - 524288;
        int k = t >> 8, n = t & 255;
        w1t[n * 512 + k] = (__bf16)W1[t];
    } else if (j < 524288 + 131072 + 32768) { // W2 [256][128] -> W2T [128][256]
        int t = j - 655360;
        int k = t >> 7, n = t & 127;
        w2t[n * 256 + k] = (__bf16)W2[t];
    }
}

// ---- small bf16 GEMM, C (bf16) = X * Y^T ----
template<int MT, int WC>
__global__ __launch_bounds__(256, 2) void gemm_bt_cbf16(
    const __bf16* __restrict__ X, const __bf16* __restrict__ Yb,
    __bf16* __restrict__ C, int K, int N)
{
    constexpr int WR = 4 / WC;
    constexpr int BM = WR * MT * 16;
    constexpr int BN = WC * 64;
    const int mblk = blockIdx.x, nblk = blockIdx.y;
    const int w = threadIdx.x >> 6, lane = threadIdx.x & 63;
    const int wr = w / WC, wc = w % WC;
    const int q = lane >> 4, l16 = lane & 15;
    const int mbase = mblk * BM + wr * (MT * 16);
    const int nbase = nblk * BN + wc * 64;

    f32x4_t acc[MT][4];
    const f32x4_t z = {0.f, 0.f, 0.f, 0.f};
#pragma unroll
    for (int i = 0; i < MT; i++)
#pragma unroll
        for (int jj = 0; jj < 4; jj++) acc[i][jj] = z;

    const __bf16* Xr[MT];
    const __bf16* Yr[4];
#pragma unroll
    for (int i = 0; i < MT; i++) Xr[i] = X + (size_t)(mbase + i * 16 + l16) * K + q * 8;
#pragma unroll
    for (int jj = 0; jj < 4; jj++) Yr[jj] = Yb + (size_t)(nbase + jj * 16 + l16) * K + q * 8;

    for (int k = 0; k < K; k += 32) {
        bf16x8_t a[MT], b[4];
#pragma unroll
        for (int i = 0; i < MT; i++) a[i] = *(const bf16x8_t*)(Xr[i] + k);
#pragma unroll
        for (int jj = 0; jj < 4; jj++) b[jj] = *(const bf16x8_t*)(Yr[jj] + k);
#pragma unroll
        for (int i = 0; i < MT; i++)
#pragma unroll
            for (int jj = 0; jj < 4; jj++) acc[i][jj] = MFMA_BF16(a[i], b[jj], acc[i][jj]);
    }

#pragma unroll
    for (int i = 0; i < MT; i++)
#pragma unroll
        for (int jj = 0; jj < 4; jj++) {
            const int row0 = mbase + i * 16 + q * 4;
            const int col = nbase + jj * 16 + l16;
#pragma unroll
            for (int r = 0; r < 4; r++)
                C[(size_t)(row0 + r) * N + col] = (__bf16)acc[i][jj][r];
        }
}

// ---- adj GEMM: fp32 A staged via NT global_load_lds into double-buffered LDS
// (64x64 tile, 16 KB), source-column XOR swizzle @16B. Wave-grid 1x4: each
// wave computes all 64 rows (MT=4) x NN/4 cols. B (Y) loaded per-wave from
// global — duplication-free at this blocking, L2-resident since adj is NT.
// b-loads issued BEFORE the barrier so in-order vmcnt never forces a
// mid-iteration drain of the prefetch. ----
template<int NN>
__global__ __launch_bounds__(256, 2) void gemm_adj_lds(
    const float* __restrict__ A, const __bf16* __restrict__ Y,
    float* __restrict__ P, int kchunk)
{
    constexpr int NT = NN / 64;          // n-tiles per wave (1x4 wave grid)
    __shared__ float As[2][4096];        // 2 x 64 rows x 64 cols fp32

    const int mblk = blockIdx.x;
    const int ks = blockIdx.y;
    const int w = threadIdx.x >> 6, lane = threadIdx.x & 63;
    const int q = lane >> 4, l16 = lane & 15;
    const int kbase = ks * kchunk;
    const int ntiles = kchunk >> 6;

    // staging: wave-instr (w, j) covers tile rows j*16+w*4 .. +4.
    // LDS dst = uniform base + lane*16 (DMA constraint); global source column
    // XOR-swizzled: granule g at row r holds A[.., kk + ((g ^ (r&15))*4)].
    const int lrow = lane >> 4;
    const int lg = lane & 15;
    const float* gsrc[4];
    int loff[4];
#pragma unroll
    for (int j = 0; j < 4; j++) {
        const int row = j * 16 + w * 4 + lrow;
        const int colswz = ((lg ^ (row & 15)) << 2);
        gsrc[j] = A + (size_t)(mblk * 64 + row) * 8192 + kbase + colswz;
        loff[j] = row * 64 + (lg << 2);
    }

    const __bf16* Yr[NT];
#pragma unroll
    for (int jj = 0; jj < NT; jj++)
        Yr[jj] = Y + (size_t)(w * (NN / 4) + jj * 16 + l16) * 8192 + q * 8;

    f32x4_t acc[4][NT];
    const f32x4_t z = {0.f, 0.f, 0.f, 0.f};
#pragma unroll
    for (int i = 0; i < 4; i++)
#pragma unroll
        for (int jj = 0; jj < NT; jj++) acc[i][jj] = z;

    // preload tile 0 (NT cpol: don't pollute L2 with streaming adj)
#pragma unroll
    for (int j = 0; j < 4; j++) gload_lds16<2>(gsrc[j], &As[0][0] + loff[j]);

    int buf = 0;
    for (int kt = 0; kt < ntiles; kt++) {
        const int kk = kbase + (kt << 6);

        // B fragments for this K-tile, issued BEFORE the barrier: they are
        // L2-hits and complete during the barrier's DMA drain.
        bf16x8_t breg[2][NT];
#pragma unroll
        for (int s = 0; s < 2; s++)
#pragma unroll
            for (int jj = 0; jj < NT; jj++)
                breg[s][jj] = *(const bf16x8_t*)(Yr[jj] + kk + s * 32);

        __syncthreads();   // tile kt DMA complete; prev compute done

        if (kt + 1 < ntiles) {
            const int koff = (kt + 1) << 6;
#pragma unroll
            for (int j = 0; j < 4; j++)
                gload_lds16<2>(gsrc[j] + koff, &As[buf ^ 1][0] + loff[j]);
        }

        const float* __restrict__ L = &As[buf][0];
#pragma unroll
        for (int s = 0; s < 2; s++) {
            bf16x8_t a[4];
#pragma unroll
            for (int i = 0; i < 4; i++) {
                const int r = i * 16 + l16;              // tile-local row
                const int g0 = ((s * 8 + q * 2) ^ l16) << 2;
                const int g1 = ((s * 8 + q * 2 + 1) ^ l16) << 2;
                f32x4_t u = *(const f32x4_t*)(L + r * 64 + g0);
                f32x4_t v = *(const f32x4_t*)(L + r * 64 + g1);
                a[i] = cvt8(u, v);
            }
#pragma unroll
            for (int i = 0; i < 4; i++)
#pragma unroll
                for (int jj = 0; jj < NT; jj++)
                    acc[i][jj] = MFMA_BF16(a[i], breg[s][jj], acc[i][jj]);
        }
        buf ^= 1;
    }

    // NT partial stores: write-once stream, don't evict the B panel from L2
#pragma unroll
    for (int i = 0; i < 4; i++)
#pragma unroll
        for (int jj = 0; jj < NT; jj++) {
            const int row0 = mblk * 64 + i * 16 + q * 4;
            const int col = w * (NN / 4) + jj * 16 + l16;
            float* pp = P + ((size_t)ks * 8192 + row0) * NN + col;
#pragma unroll
            for (int r = 0; r < 4; r++)
                __builtin_nontemporal_store(acc[i][jj][r], pp + (size_t)r * NN);
        }
}

// ---- epilogue 1: h1 = relu(sum_ks partial + b1) -> bf16 [8192][256] ----
__global__ __launch_bounds__(256) void epi_relu_bias(
    const float* __restrict__ P, const float* __restrict__ bias,
    __bf16* __restrict__ H)
{
    const size_t SL = (size_t)8192 * 256;
    const size_t idx = ((size_t)blockIdx.x * 256 + threadIdx.x) * 4;
    f32x4_t s0 = nt_load4(P + idx);
    f32x4_t s1 = nt_load4(P + SL + idx);
    f32x4_t s2 = nt_load4(P + 2 * SL + idx);
    f32x4_t s3 = nt_load4(P + 3 * SL + idx);
    const int col = (int)(idx & 255);
    f32x4_t bb = *(const f32x4_t*)(bias + col);
    bf16x4_t o;
#pragma unroll
    for (int e = 0; e < 4; e++)
        o[e] = (__bf16)fmaxf(s0[e] + s1[e] + s2[e] + s3[e] + bb[e], 0.f);
    *(bf16x4_t*)(H + idx) = o;   // cacheable: re-read by t2T GEMM
}

// ---- epilogue 2: h = sum_ks partial + b2 -> fp32 d_out tail AND bf16 copy ----
__global__ __launch_bounds__(256) void epi_bias_out(
    const float* __restrict__ P, const float* __restrict__ bias,
    float* __restrict__ Hout, __bf16* __restrict__ Hbf)
{
    const size_t SL = (size_t)8192 * 128;
    const size_t idx = ((size_t)blockIdx.x * 256 + threadIdx.x) * 4;
    f32x4_t s0 = nt_load4(P + idx);
    f32x4_t s1 = nt_load4(P + SL + idx);
    f32x4_t s2 = nt_load4(P + 2 * SL + idx);
    f32x4_t s3 = nt_load4(P + 3 * SL + idx);
    const int col = (int)(idx & 127);
    f32x4_t bb = *(const f32x4_t*)(bias + col);
    f32x4_t o;
#pragma unroll
    for (int e = 0; e < 4; e++)
        o[e] = s0[e] + s1[e] + s2[e] + s3[e] + bb[e];
    nt_store4(o, Hout + idx);   // write-once tail of d_out
    bf16x4_t ob;
#pragma unroll
    for (int e = 0; e < 4; e++) ob[e] = (__bf16)o[e];
    *(bf16x4_t*)(Hbf + idx) = ob;   // cacheable: re-read 128x by gemm_sig
}

// ---- decoder: out[r][s] = sigmoid(h[r,:].h[s,:]), K=128 unrolled ----
__global__ __launch_bounds__(256, 2) void gemm_sig(
    const __bf16* __restrict__ H, float* __restrict__ out)
{
    const int mblk = blockIdx.x, nblk = blockIdx.y;
    const int w = threadIdx.x >> 6, lane = threadIdx.x & 63;
    const int wr = w >> 1, wc = w & 1;
    const int q = lane >> 4, l16 = lane & 15;
    const int mbase = mblk * 128 + wr * 64;
    const int nbase = nblk * 128 + wc * 64;

    f32x4_t acc[4][4];
    const f32x4_t z = {0.f, 0.f, 0.f, 0.f};
#pragma unroll
    for (int i = 0; i < 4; i++)
#pragma unroll
        for (int jj = 0; jj < 4; jj++) acc[i][jj] = z;

#pragma unroll
    for (int k = 0; k < 128; k += 32) {
        bf16x8_t a[4], b[4];
#pragma unroll
        for (int i = 0; i < 4; i++)
            a[i] = *(const bf16x8_t*)(H + (size_t)(mbase + i * 16 + l16) * 128 + k + q * 8);
#pragma unroll
        for (int jj = 0; jj < 4; jj++)
            b[jj] = *(const bf16x8_t*)(H + (size_t)(nbase + jj * 16 + l16) * 128 + k + q * 8);
#pragma unroll
        for (int i = 0; i < 4; i++)
#pragma unroll
            for (int jj = 0; jj < 4; jj++) acc[i][jj] = MFMA_BF16(a[i], b[jj], acc[i][jj]);
    }

    // NT stores: out is a 268 MB write-once stream; keeping it out of L2
    // preserves the 2 MB H panel across the 64x re-reads.
#pragma unroll
    for (int i = 0; i < 4; i++)
#pragma unroll
        for (int jj = 0; jj < 4; jj++) {
            const int row0 = mbase + i * 16 + q * 4;
            const int col = nbase + jj * 16 + l16;
#pragma unroll
            for (int r = 0; r < 4; r++) {
                float x = acc[i][jj][r];
                float s = 1.0f / (1.0f + __expf(-x));
                __builtin_nontemporal_store(s, out + (size_t)(row0 + r) * 8192 + col);
            }
        }
}

extern "C" void kernel_launch(void* const* d_in, const int* in_sizes, int n_in,
                              void* d_out, int out_size, void* d_ws, size_t ws_size,
                              hipStream_t stream)
{
    const float* adj  = (const float*)d_in[0];
    const float* feat = (const float*)d_in[1];
    const float* W1   = (const float*)d_in[2];
    const float* b1   = (const float*)d_in[3];
    const float* W2   = (const float*)d_in[4];
    const float* b2   = (const float*)d_in[5];
    float* out = (float*)d_out;

    // workspace layout (~52.3 MB total)
    char* p = (char*)d_ws;
    __bf16* featbf = (__bf16*)p; p += (size_t)8192 * 512 * 2;  // 8 MB
    __bf16* W1T    = (__bf16*)p; p += (size_t)256 * 512 * 2;   // 256 KB
    __bf16* W2T    = (__bf16*)p; p += (size_t)128 * 256 * 2;   // 64 KB
    __bf16* t1T    = (__bf16*)p; p += (size_t)256 * 8192 * 2;  // 4 MB
    __bf16* h1     = (__bf16*)p; p += (size_t)8192 * 256 * 2;  // 4 MB
    __bf16* t2T    = (__bf16*)p; p += (size_t)128 * 8192 * 2;  // 2 MB
    __bf16* hbf    = (__bf16*)p; p += (size_t)8192 * 128 * 2;  // 2 MB
    float* part    = (float*)p;                                 // 32 MB (reused 16 MB)

    // 1. casts
    cast_all<<<2688, 256, 0, stream>>>(feat, W1, W2, featbf, W1T, W2T);
    // 2. t1T[256][8192] = W1T * feat^T
    gemm_bt_cbf16<2, 2><<<dim3(4, 64), 256, 0, stream>>>(W1T, featbf, t1T, 512, 8192);
    // 3. partials of adj @ t1  (split-K=4, LDS-staged, NT adj)
    gemm_adj_lds<256><<<dim3(128, 4), 256, 0, stream>>>(adj, t1T, part, 2048);
    // 4. h1 = relu(sum + b1) -> bf16
    epi_relu_bias<<<2048, 256, 0, stream>>>(part, b1, h1);
    // 5. t2T[128][8192] = W2T * h1^T
    gemm_bt_cbf16<2, 2><<<dim3(2, 64), 256, 0, stream>>>(W2T, h1, t2T, 256, 8192);
    // 6. partials of adj @ t2  (split-K=4, LDS-staged, NT adj)
    gemm_adj_lds<128><<<dim3(128, 4), 256, 0, stream>>>(adj, t2T, part, 2048);
    // 7. h = sum + b2 -> fp32 out tail + bf16 copy
    epi_bias_out<<<1024, 256, 0, stream>>>(part, b2, out + (size_t)8192 * 8192, hbf);
    // 8. out = sigmoid(h @ h^T)
    gemm_sig<<<dim3(64, 64), 256, 0, stream>>>(hbf, out);
}